// Round 6
// baseline (9222.249 us; speedup 1.0000x reference)
//
#include <hip/hip_runtime.h>
#include <cstdint>
#include <cstddef>

// ============================================================================
// Persistent fused 2-layer LSTM + FC for MI355X (gfx950) — Round 11:
// SPLIT-PHASE DATAFLOW (dual generations). R10 = 8666us (17.2us/round),
// VALUBusy 1.76% => ~16us/round is still sync wait; R10's round serializes
// stage -> L0+L1+FC -> finalize -> full barrier, but only L0->h1[r] is truly
// on the per-round critical path (L1 eats h1[r-1],h2[r-2]; FC eats h2[r-2];
// h2[r-1] not needed before round r+1). Changes vs R10:
//   1. Two flag/gen pairs per half: (fA,genA) = h1, (fB,genB) = h2.
//      Top-of-round wait: genA >= r-1 AND genB >= r-2 (latter ~always ready).
//   2. After the L0-zone sync, wave0 finalizes h1[r], sc1-stores the 256B
//      record, s_waitcnt vmcnt(0), posts fA[bh]=r. Block bh==0's wave0 then
//      sweeps fA and publishes genA=r. Waves 1-7 are ALREADY doing L1/FC
//      MFMA meanwhile; wave0 joins L1 late (its K-chunks), meets at sync.
//   3. Wave1 finalizes h2[r-1] -> record + fB post (bh==1's wave1 sweeps,
//      publishes genB=r-1); wave2 writes FC. NO end-of-round barrier:
//      L1/FC + h2 convergence run in the shadow of next round's L0 wait.
//   4. All cross-block ops stay RELAXED (no wbl2/inv); ordering = manual
//      vmcnt(0) between record store and flag post; consumers read fresh
//      per-round addresses (plain cached) strictly after gen observation
//      (validated in R10).
// Kept from R10: half split (bk&1), M=16 B-tile / two A-tiles, padded LDS
// rows (1034), zone reduction, gate math, record/stage layouts.
// ============================================================================

#define NBLK 256
#define NTHR 512

typedef _Float16 f16;
typedef _Float16 f16x8 __attribute__((ext_vector_type(8)));
typedef float f32x4 __attribute__((ext_vector_type(4)));
typedef unsigned long long u64;

namespace {
constexpr int kB = 32, kT = 512, kI = 256, kH = 1024, kO = 512, kTR = 500;
constexpr int kRounds = 502;
constexpr size_t kSlots = 503;
constexpr size_t kHalfSlot = 32768;                  // 16 b x 1024 u x f16
// workspace layout (bytes)
constexpr size_t kH1Off = 8192;                      // flags in [0,8192)
constexpr size_t kH2Off = kH1Off + kSlots * 2 * kHalfSlot;
// flag word indices within a half's 1024-word region (half*4096 bytes):
constexpr int kFA = 0;                               // fA[0..127]
constexpr int kGenA = 192;                           // own line
constexpr int kFB = 256;                             // fB[0..127]
constexpr int kGenB = 448;                           // own line
// LDS: h1 stage [16][1034] f16 | h2 stage same | zone 5*16*17 f32
constexpr int kStageRow = 1034;                      // f16 per b-row (pad 10)
constexpr int kH2Lds = 16 * kStageRow;               // f16 index 16544
constexpr int kZoneF = 5 * 16 * 17;                  // 1360 f32
constexpr int kLdsBytes = 2 * kH2Lds * 2 + kZoneF * 4;  // 71616
}

__device__ __forceinline__ unsigned ld_agent_u32(const unsigned* p) {
  return __hip_atomic_load(p, __ATOMIC_RELAXED, __HIP_MEMORY_SCOPE_AGENT);
}
__device__ __forceinline__ void st_agent_u32(void* p, unsigned v) {
  __hip_atomic_store((unsigned*)p, v, __ATOMIC_RELAXED,
                     __HIP_MEMORY_SCOPE_AGENT);
}

__device__ __forceinline__ float sigmoid_f(float x) {
  return __builtin_amdgcn_rcpf(1.f + __expf(-x));
}
__device__ __forceinline__ float tanh_f(float x) {
  return 1.f - 2.f * __builtin_amdgcn_rcpf(1.f + __expf(2.f * x));
}
__device__ __forceinline__ f16x8 load8(const float* p) {
  f16x8 r;
#pragma unroll
  for (int j = 0; j < 8; ++j) r[j] = (f16)p[j];
  return r;
}

__global__ void __launch_bounds__(256, 1) lstm_init_kernel(char* ws) {
  const int gid = blockIdx.x * 256 + threadIdx.x;     // 32768 threads
  unsigned* flags = (unsigned*)ws;
  if (gid < 2048) flags[gid] = 0u;
  // zero slot 0 (both halves) of h1 and h2: 64KB each = 8192 u64
  u64* r1 = (u64*)(ws + kH1Off);
  u64* r2 = (u64*)(ws + kH2Off);
  if (gid < 8192) { r1[gid] = 0ull; r2[gid] = 0ull; }
}

__global__ void __launch_bounds__(NTHR, 1) __attribute__((amdgpu_waves_per_eu(2)))
lstm_mfma_kernel(const float* __restrict__ x,
                 const float* __restrict__ Wih0, const float* __restrict__ Whh0,
                 const float* __restrict__ bih0, const float* __restrict__ bhh0,
                 const float* __restrict__ Wih1, const float* __restrict__ Whh1,
                 const float* __restrict__ bih1, const float* __restrict__ bhh1,
                 const float* __restrict__ Wfc, const float* __restrict__ bfc,
                 float* __restrict__ out, char* __restrict__ ws) {
  const int tid = threadIdx.x;
  const int bk = blockIdx.x;
  const int half = bk & 1;                // batch half: rows half*16..+15
  const int bh = bk >> 1;                 // block-in-half 0..127
  const int w = tid >> 6;                 // wave 0..7
  const int lane = tid & 63;
  const int m = lane & 15;                // A row / B col (batch) / D col
  const int kg = lane >> 4;               // k-group 0..3
  const int q = m >> 2, g = m & 3;        // A-row -> (unit-in-tile, gate)
  const int U0 = bh * 8;                  // owned unit base (both layers)

  unsigned* fl = (unsigned*)ws + (size_t)half * 1024;  // per-half flag region
  extern __shared__ f16 lds[];
  float* zone = (float*)((char*)lds + 2 * kH2Lds * 2);  // 5*272 f32

  // ---- one-time A-fragment (weight) preload, f16 in VGPRs ----
  f16x8 wA0[4], wA1[4], wI0[4], wI1[4], wR0[4], wR1[4], wF[4], wX0, wX1;
#pragma unroll
  for (int i = 0; i < 4; ++i) {
    const size_t kc = (size_t)(w + 8 * i) * 32 + kg * 8;
    wA0[i] = load8(Whh0 + (size_t)(g * kH + U0 + q) * kH + kc);
    wA1[i] = load8(Whh0 + (size_t)(g * kH + U0 + 4 + q) * kH + kc);
    wI0[i] = load8(Wih1 + (size_t)(g * kH + U0 + q) * kH + kc);
    wI1[i] = load8(Wih1 + (size_t)(g * kH + U0 + 4 + q) * kH + kc);
    wR0[i] = load8(Whh1 + (size_t)(g * kH + U0 + q) * kH + kc);
    wR1[i] = load8(Whh1 + (size_t)(g * kH + U0 + 4 + q) * kH + kc);
  }
  wX0 = load8(Wih0 + (size_t)(g * kH + U0 + q) * kI + w * 32 + kg * 8);
  wX1 = load8(Wih0 + (size_t)(g * kH + U0 + 4 + q) * kI + w * 32 + kg * 8);
#pragma unroll
  for (int i = 0; i < 4; ++i) {           // FC rows: m<4 valid (o = bh*4+m)
    f16x8 v = load8(Wfc + (size_t)(bh * 4 + (m < 4 ? m : 0)) * kH +
                    (size_t)(w + 8 * i) * 32 + kg * 8);
    if (m >= 4) {
#pragma unroll
      for (int j = 0; j < 8; ++j) v[j] = (f16)0.f;
    }
    wF[i] = v;
  }
  // biases for finalize: lane -> (b = lane>>2, p = lane&3), units U0+2p+s
  const int pb = lane & 3;
  float biasL0[2][4], biasL1[2][4];
#pragma unroll
  for (int s = 0; s < 2; ++s) {
#pragma unroll
    for (int j = 0; j < 4; ++j) {
      const int uq = U0 + 2 * pb + s;
      biasL0[s][j] = bih0[j * kH + uq] + bhh0[j * kH + uq];
      biasL1[s][j] = bih1[j * kH + uq] + bhh1[j * kH + uq];
    }
  }
  const float bfc_l = bfc[bh * 4 + (lane & 3)];
  float cL0[2] = {0.f, 0.f}, cL1[2] = {0.f, 0.f};

  // stage addressing: 16B chunk i = tid + 512j -> rec = i>>4, b = tid&15
  f16* d1 = lds + (tid & 15) * kStageRow + (tid >> 4) * 8;
  f16* d2 = d1 + kH2Lds;

  for (int r = 1; r <= kRounds; ++r) {
    // ---- top-of-round dependency wait: h1[r-1] ready, h2[r-2] ready
    if (tid == 0) {
      while (ld_agent_u32(&fl[kGenA]) < (unsigned)(r - 1))
        __builtin_amdgcn_s_sleep(1);
      if (r >= 3) {
        while (ld_agent_u32(&fl[kGenB]) < (unsigned)(r - 2))
          __builtin_amdgcn_s_sleep(1);
      }
    }
    __syncthreads();

    // ---- zero reduction zone (overlaps staging load latency)
    for (int i = tid; i < kZoneF; i += NTHR) zone[i] = 0.f;
    // ---- stage h1[r-1], h2[max(r-2,0)] (own half): plain cached 16B loads
    {
      const char* s1 =
          ws + kH1Off + ((size_t)(r - 1) * 2 + half) * kHalfSlot;
      const char* s2 =
          ws + kH2Off + ((size_t)(r >= 2 ? r - 2 : 0) * 2 + half) * kHalfSlot;
      f16x8 a[4], c4[4];
#pragma unroll
      for (int j = 0; j < 4; ++j) {
        a[j] = *(const f16x8*)(s1 + ((size_t)tid + 512 * j) * 16);
        c4[j] = *(const f16x8*)(s2 + ((size_t)tid + 512 * j) * 16);
      }
#pragma unroll
      for (int j = 0; j < 4; ++j) {
        *(f16x8*)(d1 + (size_t)j * 256) = a[j];
        *(f16x8*)(d2 + (size_t)j * 256) = c4[j];
      }
    }
    __syncthreads();

    // ================= L0: D = Whh0 @ h1[r-1] + Wih0 @ x[r-1] ==============
    {
      f32x4 a0 = {0.f, 0.f, 0.f, 0.f}, a1 = {0.f, 0.f, 0.f, 0.f};
#pragma unroll
      for (int i = 0; i < 4; ++i) {
        const int k = (w + 8 * i) * 32 + kg * 8;
        f16x8 bf = *(const f16x8*)(lds + m * kStageRow + k);
        a0 = __builtin_amdgcn_mfma_f32_16x16x32_f16(wA0[i], bf, a0, 0, 0, 0);
        a1 = __builtin_amdgcn_mfma_f32_16x16x32_f16(wA1[i], bf, a1, 0, 0, 0);
      }
      {  // x chunk: K' = w*32 .. w*32+31 of I=256
        const int kp = w * 32 + kg * 8;
        f16x8 bf =
            load8(x + ((size_t)(half * 16 + m) * kT + (r - 1)) * kI + kp);
        a0 = __builtin_amdgcn_mfma_f32_16x16x32_f16(wX0, bf, a0, 0, 0, 0);
        a1 = __builtin_amdgcn_mfma_f32_16x16x32_f16(wX1, bf, a1, 0, 0, 0);
      }
#pragma unroll
      for (int j = 0; j < 4; ++j) {
        atomicAdd(&zone[0 * 272 + (kg * 4 + j) * 17 + m], a0[j]);
        atomicAdd(&zone[1 * 272 + (kg * 4 + j) * 17 + m], a1[j]);
      }
    }
    __syncthreads();                      // L0 zones complete

    // ---- wave0: finalize h1[r] -> record + fA post (+ sweep if bh==0);
    //      waves 1-7 proceed straight into L1; wave0 joins L1 after.
    if (w == 0) {
      const int b = lane >> 2, p = lane & 3;
      f16 hv[2];
#pragma unroll
      for (int s = 0; s < 2; ++s) {
        const int u = 2 * p + s;
        const float* z = zone + (u >> 2) * 272;
        const int rq = (u & 3) * 4;
        const float pi = z[(rq + 0) * 17 + b] + biasL0[s][0];
        const float pf = z[(rq + 1) * 17 + b] + biasL0[s][1];
        const float pg = z[(rq + 2) * 17 + b] + biasL0[s][2];
        const float po = z[(rq + 3) * 17 + b] + biasL0[s][3];
        float cc = cL0[s];
        cc = sigmoid_f(pf) * cc + sigmoid_f(pi) * tanh_f(pg);
        cL0[s] = cc;
        hv[s] = (f16)(sigmoid_f(po) * tanh_f(cc));
      }
      unsigned pk;
      __builtin_memcpy(&pk, hv, 4);
      st_agent_u32(ws + kH1Off + ((size_t)r * 2 + half) * kHalfSlot +
                       bh * 256 + b * 16 + p * 4,
                   pk);
      asm volatile("s_waitcnt vmcnt(0)" ::: "memory");  // drain record store
      if (lane == 0) st_agent_u32(&fl[kFA + bh], (unsigned)r);
      if (bh == 0) {                      // sweep fA, publish genA = r
        const int l2 = lane << 1;
        bool done;
        do {
          unsigned ok =
              (unsigned)(ld_agent_u32(&fl[kFA + l2]) >= (unsigned)r) &
              (unsigned)(ld_agent_u32(&fl[kFA + l2 + 1]) >= (unsigned)r);
          done = __all((int)ok);
          if (!done) __builtin_amdgcn_s_sleep(1);
        } while (!done);
        if (lane == 0) st_agent_u32(&fl[kGenA], (unsigned)r);
      }
    }

    // ================= L1: D = Wih1 @ h1[r-1] + Whh1 @ h2[r-2] =============
    {
      f32x4 a2 = {0.f, 0.f, 0.f, 0.f}, a3 = {0.f, 0.f, 0.f, 0.f};
#pragma unroll
      for (int i = 0; i < 4; ++i) {
        const int k = (w + 8 * i) * 32 + kg * 8;
        f16x8 bf = *(const f16x8*)(lds + m * kStageRow + k);
        a2 = __builtin_amdgcn_mfma_f32_16x16x32_f16(wI0[i], bf, a2, 0, 0, 0);
        a3 = __builtin_amdgcn_mfma_f32_16x16x32_f16(wI1[i], bf, a3, 0, 0, 0);
      }
#pragma unroll
      for (int i = 0; i < 4; ++i) {
        const int k = (w + 8 * i) * 32 + kg * 8;
        f16x8 bf = *(const f16x8*)(lds + kH2Lds + m * kStageRow + k);
        a2 = __builtin_amdgcn_mfma_f32_16x16x32_f16(wR0[i], bf, a2, 0, 0, 0);
        a3 = __builtin_amdgcn_mfma_f32_16x16x32_f16(wR1[i], bf, a3, 0, 0, 0);
      }
#pragma unroll
      for (int j = 0; j < 4; ++j) {
        atomicAdd(&zone[2 * 272 + (kg * 4 + j) * 17 + m], a2[j]);
        atomicAdd(&zone[3 * 272 + (kg * 4 + j) * 17 + m], a3[j]);
      }
    }
    // ---- FC: D = Wfc @ h2[r-2]   (rows 0..3 valid -> o = bh*4+row)
    {
      f32x4 a4 = {0.f, 0.f, 0.f, 0.f};
#pragma unroll
      for (int i = 0; i < 4; ++i) {
        const int k = (w + 8 * i) * 32 + kg * 8;
        f16x8 bf = *(const f16x8*)(lds + kH2Lds + m * kStageRow + k);
        a4 = __builtin_amdgcn_mfma_f32_16x16x32_f16(wF[i], bf, a4, 0, 0, 0);
      }
      if (kg == 0) {
#pragma unroll
        for (int j = 0; j < 4; ++j)
          atomicAdd(&zone[4 * 272 + j * 17 + m], a4[j]);
      }
    }
    __syncthreads();                      // L1/FC zones complete

    // ---- wave1: finalize h2[r-1] -> record + fB post (+ sweep if bh==1);
    //      wave2: FC -> out.  No end-of-round barrier.
    if (w == 1 && r >= 2) {
      const int b = lane >> 2, p = lane & 3;
      f16 hv[2];
#pragma unroll
      for (int s = 0; s < 2; ++s) {
        const int u = 2 * p + s;
        const float* z = zone + (2 + (u >> 2)) * 272;
        const int rq = (u & 3) * 4;
        const float pi = z[(rq + 0) * 17 + b] + biasL1[s][0];
        const float pf = z[(rq + 1) * 17 + b] + biasL1[s][1];
        const float pg = z[(rq + 2) * 17 + b] + biasL1[s][2];
        const float po = z[(rq + 3) * 17 + b] + biasL1[s][3];
        float cc = cL1[s];
        cc = sigmoid_f(pf) * cc + sigmoid_f(pi) * tanh_f(pg);
        cL1[s] = cc;
        hv[s] = (f16)(sigmoid_f(po) * tanh_f(cc));
      }
      unsigned pk;
      __builtin_memcpy(&pk, hv, 4);
      st_agent_u32(ws + kH2Off + ((size_t)(r - 1) * 2 + half) * kHalfSlot +
                       bh * 256 + b * 16 + p * 4,
                   pk);
      asm volatile("s_waitcnt vmcnt(0)" ::: "memory");
      if (lane == 0) st_agent_u32(&fl[kFB + bh], (unsigned)(r - 1));
      if (bh == 1) {                      // sweep fB, publish genB = r-1
        const int l2 = lane << 1;
        bool done;
        do {
          unsigned ok =
              (unsigned)(ld_agent_u32(&fl[kFB + l2]) >= (unsigned)(r - 1)) &
              (unsigned)(ld_agent_u32(&fl[kFB + l2 + 1]) >= (unsigned)(r - 1));
          done = __all((int)ok);
          if (!done) __builtin_amdgcn_s_sleep(1);
        } while (!done);
        if (lane == 0) st_agent_u32(&fl[kGenB], (unsigned)(r - 1));
      }
    } else if (w == 2 && r >= 3) {         // FC -> out[:, r-3, bh*4..+3]
      const int b = lane >> 2, oo = lane & 3;
      const float v = zone[4 * 272 + oo * 17 + b] + bfc_l;
      out[((size_t)(half * 16 + b) * kTR + (r - 3)) * kO + bh * 4 + oo] = v;
    }
  }
}

extern "C" void kernel_launch(void* const* d_in, const int* in_sizes, int n_in,
                              void* d_out, int out_size, void* d_ws,
                              size_t ws_size, hipStream_t stream) {
  const float* x    = (const float*)d_in[0];
  const float* Wih0 = (const float*)d_in[1];
  const float* Whh0 = (const float*)d_in[2];
  const float* bih0 = (const float*)d_in[3];
  const float* bhh0 = (const float*)d_in[4];
  const float* Wih1 = (const float*)d_in[5];
  const float* Whh1 = (const float*)d_in[6];
  const float* bih1 = (const float*)d_in[7];
  const float* bhh1 = (const float*)d_in[8];
  const float* Wfc  = (const float*)d_in[9];
  const float* bfc  = (const float*)d_in[10];
  float* out = (float*)d_out;
  char* ws   = (char*)d_ws;

  (void)hipFuncSetAttribute((const void*)lstm_mfma_kernel,
                            hipFuncAttributeMaxDynamicSharedMemorySize,
                            kLdsBytes);

  hipLaunchKernelGGL(lstm_init_kernel, dim3(128), dim3(256), 0, stream, ws);
  hipLaunchKernelGGL(lstm_mfma_kernel, dim3(NBLK), dim3(NTHR), kLdsBytes,
                     stream, x, Wih0, Whh0, bih0, bhh0, Wih1, Whh1, bih1,
                     bhh1, Wfc, bfc, out, ws);
}

// Round 7
// 8159.393 us; speedup vs baseline: 1.1303x; 1.1303x over previous
//
#include <hip/hip_runtime.h>
#include <cstdint>
#include <cstddef>

// ============================================================================
// Persistent fused 2-layer LSTM + FC for MI355X (gfx950) — Round 12:
// DIRECT TAGS + REGISTER STAGING. R11 (overlap L1/FC) = no gain => round
// period IS the h1 sync chain: finalize -> sc1 store -> vmcnt -> flag ->
// sweeper detect -> gen publish -> consumer detect -> stage -> L0. Changes:
//   1. No sweeper, no gen: producers store record (sc1), vmcnt(0), then store
//      a round-number TAG (u32) into a packed [128]-word array per (half,
//      buffer). Consumer block's wave 7 polls all 128 A-tags (>= r-1) and
//      128 B-tags (>= r-2) as TWO coalesced u64 loads (8 lines each), then
//      __syncthreads releases the block. 2 fewer LLC hops + 1 fewer
//      detection quantization per round. Poll traffic ~0.5 TB/s total
//      (256 pollers x 16 lines / ~0.5us) — 100x below R8's storm.
//   2. LDS staging DELETED: record layout [b:16][16B] makes every MFMA
//      B-frag a contiguous 16B slice; each wave loads its 4 h1-frags +
//      4 h2-frags (1KB coalesced per frag set) straight into VGPRs via
//      plain cached loads (L2-dedup across the 16 blocks/XCD — R10-
//      validated freshness: every data address read exactly once, after
//      tag observation). h1 frags feed L0 AND L1; h2 frags feed L1 AND FC.
//   3. Zones zeroed by their finalize-readers (wave0: tiles 0-1, wave1:
//      2-3, wave2: 4) — race-free under the 3 intra-block syncs.
// Kept from R10/R11: half split (bk&1), M=16 B-tile + two A-tiles, relaxed
// agent-scope everywhere (no wbl2/inv), record layout, gate math, schedule.
// ============================================================================

#define NBLK 256
#define NTHR 512

typedef _Float16 f16;
typedef _Float16 f16x8 __attribute__((ext_vector_type(8)));
typedef float f32x4 __attribute__((ext_vector_type(4)));
typedef unsigned long long u64;

namespace {
constexpr int kB = 32, kT = 512, kI = 256, kH = 1024, kO = 512, kTR = 500;
constexpr int kRounds = 502;
constexpr size_t kHalfSlot = 32768;                  // 16 b x 1024 u x f16
// workspace layout (bytes):
// [0,4096): tags. half h at ws + h*1024: A-tags u32[128] at +0 (512B),
//           B-tags u32[128] at +512.
constexpr size_t kH1Off = 4096;
constexpr size_t kH2Off = kH1Off + 503ull * 2 * kHalfSlot;
// LDS: zones only: 5 tiles x 16 x 17 f32
constexpr int kZoneF = 5 * 16 * 17;                  // 1360 f32
constexpr int kLdsBytes = kZoneF * 4;                // 5440
}

__device__ __forceinline__ u64 ld_agent_u64(const void* p) {
  return __hip_atomic_load((const u64*)p, __ATOMIC_RELAXED,
                           __HIP_MEMORY_SCOPE_AGENT);
}
__device__ __forceinline__ void st_agent_u32(void* p, unsigned v) {
  __hip_atomic_store((unsigned*)p, v, __ATOMIC_RELAXED,
                     __HIP_MEMORY_SCOPE_AGENT);
}

__device__ __forceinline__ float sigmoid_f(float x) {
  return __builtin_amdgcn_rcpf(1.f + __expf(-x));
}
__device__ __forceinline__ float tanh_f(float x) {
  return 1.f - 2.f * __builtin_amdgcn_rcpf(1.f + __expf(2.f * x));
}
__device__ __forceinline__ f16x8 load8(const float* p) {
  f16x8 r;
#pragma unroll
  for (int j = 0; j < 8; ++j) r[j] = (f16)p[j];
  return r;
}

__global__ void __launch_bounds__(256, 1) lstm_init_kernel(char* ws) {
  const int gid = blockIdx.x * 256 + threadIdx.x;     // 32768 threads
  unsigned* flags = (unsigned*)ws;
  if (gid < 1024) flags[gid] = 0u;                    // tags region
  // zero slot 0 (both halves) of h1 and h2: 64KB each = 8192 u64
  u64* r1 = (u64*)(ws + kH1Off);
  u64* r2 = (u64*)(ws + kH2Off);
  if (gid < 8192) { r1[gid] = 0ull; r2[gid] = 0ull; }
}

__global__ void __launch_bounds__(NTHR, 1) __attribute__((amdgpu_waves_per_eu(2)))
lstm_mfma_kernel(const float* __restrict__ x,
                 const float* __restrict__ Wih0, const float* __restrict__ Whh0,
                 const float* __restrict__ bih0, const float* __restrict__ bhh0,
                 const float* __restrict__ Wih1, const float* __restrict__ Whh1,
                 const float* __restrict__ bih1, const float* __restrict__ bhh1,
                 const float* __restrict__ Wfc, const float* __restrict__ bfc,
                 float* __restrict__ out, char* __restrict__ ws) {
  const int tid = threadIdx.x;
  const int bk = blockIdx.x;
  const int half = bk & 1;                // batch half: rows half*16..+15
  const int bh = bk >> 1;                 // block-in-half 0..127
  const int w = tid >> 6;                 // wave 0..7
  const int lane = tid & 63;
  const int m = lane & 15;                // A row / B col (batch) / D col
  const int kg = lane >> 4;               // k-group 0..3
  const int q = m >> 2, g = m & 3;        // A-row -> (unit-in-tile, gate)
  const int U0 = bh * 8;                  // owned unit base (both layers)

  char* tagbase = ws + (size_t)half * 1024;   // A u32[128] | +512 B u32[128]
  extern __shared__ float zone[];             // 5*272 f32

  // ---- one-time A-fragment (weight) preload, f16 in VGPRs ----
  f16x8 wA0[4], wA1[4], wI0[4], wI1[4], wR0[4], wR1[4], wF[4], wX0, wX1;
#pragma unroll
  for (int i = 0; i < 4; ++i) {
    const size_t kc = (size_t)(w + 8 * i) * 32 + kg * 8;
    wA0[i] = load8(Whh0 + (size_t)(g * kH + U0 + q) * kH + kc);
    wA1[i] = load8(Whh0 + (size_t)(g * kH + U0 + 4 + q) * kH + kc);
    wI0[i] = load8(Wih1 + (size_t)(g * kH + U0 + q) * kH + kc);
    wI1[i] = load8(Wih1 + (size_t)(g * kH + U0 + 4 + q) * kH + kc);
    wR0[i] = load8(Whh1 + (size_t)(g * kH + U0 + q) * kH + kc);
    wR1[i] = load8(Whh1 + (size_t)(g * kH + U0 + 4 + q) * kH + kc);
  }
  wX0 = load8(Wih0 + (size_t)(g * kH + U0 + q) * kI + w * 32 + kg * 8);
  wX1 = load8(Wih0 + (size_t)(g * kH + U0 + 4 + q) * kI + w * 32 + kg * 8);
#pragma unroll
  for (int i = 0; i < 4; ++i) {           // FC rows: m<4 valid (o = bh*4+m)
    f16x8 v = load8(Wfc + (size_t)(bh * 4 + (m < 4 ? m : 0)) * kH +
                    (size_t)(w + 8 * i) * 32 + kg * 8);
    if (m >= 4) {
#pragma unroll
      for (int j = 0; j < 8; ++j) v[j] = (f16)0.f;
    }
    wF[i] = v;
  }
  // biases for finalize: lane -> (b = lane>>2, p = lane&3), units U0+2p+s
  const int pb = lane & 3;
  float biasL0[2][4], biasL1[2][4];
#pragma unroll
  for (int s = 0; s < 2; ++s) {
#pragma unroll
    for (int j = 0; j < 4; ++j) {
      const int uq = U0 + 2 * pb + s;
      biasL0[s][j] = bih0[j * kH + uq] + bhh0[j * kH + uq];
      biasL1[s][j] = bih1[j * kH + uq] + bhh1[j * kH + uq];
    }
  }
  const float bfc_l = bfc[bh * 4 + (lane & 3)];
  float cL0[2] = {0.f, 0.f}, cL1[2] = {0.f, 0.f};

  // ---- pre-loop: zero all zones once ----
  for (int i = tid; i < kZoneF; i += NTHR) zone[i] = 0.f;
  __syncthreads();

  for (int r = 1; r <= kRounds; ++r) {
    // x frag is tag-independent: issue early
    const int kp = w * 32 + kg * 8;
    f16x8 bx = load8(x + ((size_t)(half * 16 + m) * kT + (r - 1)) * kI + kp);

    // ---- wave 7: poll all 128 A-tags (>= r-1) and 128 B-tags (>= r-2)
    if (w == 7) {
      const u64* pA = (const u64*)tagbase + lane;         // words 2l,2l+1
      const u64* pB = (const u64*)(tagbase + 512) + lane;
      const unsigned tgtA = (unsigned)(r - 1);
      const unsigned tgtB = (unsigned)(r >= 2 ? r - 2 : 0);
      bool done;
      do {
        const u64 va = ld_agent_u64(pA);
        const u64 vb = ld_agent_u64(pB);
        const bool ok = ((unsigned)va >= tgtA) && ((unsigned)(va >> 32) >= tgtA) &&
                        ((unsigned)vb >= tgtB) && ((unsigned)(vb >> 32) >= tgtB);
        done = __all((int)ok);
        if (!done) __builtin_amdgcn_s_sleep(1);
      } while (!done);
    }
    asm volatile("" ::: "memory");        // no load hoisting above the poll
    __syncthreads();                      // SYNC_P: tags ready for all waves

    // ---- per-wave register staging: 4 h1-frags + 4 h2-frags, plain cached
    const char* recA = ws + kH1Off + ((size_t)(r - 1) * 2 + half) * kHalfSlot;
    const char* recB =
        ws + kH2Off + ((size_t)(r >= 2 ? r - 2 : 0) * 2 + half) * kHalfSlot;
    f16x8 bf1[4], bf2[4];
#pragma unroll
    for (int i = 0; i < 4; ++i) {
      const int ro = (4 * w + 32 * i + kg) * 256 + m * 16;
      bf1[i] = *(const f16x8*)(recA + ro);
      bf2[i] = *(const f16x8*)(recB + ro);
    }

    // ================= L0: D = Whh0 @ h1[r-1] + Wih0 @ x[r-1] ==============
    {
      f32x4 a0 = {0.f, 0.f, 0.f, 0.f}, a1 = {0.f, 0.f, 0.f, 0.f};
#pragma unroll
      for (int i = 0; i < 4; ++i) {
        a0 = __builtin_amdgcn_mfma_f32_16x16x32_f16(wA0[i], bf1[i], a0, 0, 0, 0);
        a1 = __builtin_amdgcn_mfma_f32_16x16x32_f16(wA1[i], bf1[i], a1, 0, 0, 0);
      }
      a0 = __builtin_amdgcn_mfma_f32_16x16x32_f16(wX0, bx, a0, 0, 0, 0);
      a1 = __builtin_amdgcn_mfma_f32_16x16x32_f16(wX1, bx, a1, 0, 0, 0);
#pragma unroll
      for (int j = 0; j < 4; ++j) {
        atomicAdd(&zone[0 * 272 + (kg * 4 + j) * 17 + m], a0[j]);
        atomicAdd(&zone[1 * 272 + (kg * 4 + j) * 17 + m], a1[j]);
      }
    }
    __syncthreads();                      // SYNC_1: L0 zones complete

    // ---- wave0: finalize h1[r] -> record + tag; zero tiles 0-1
    if (w == 0) {
      const int b = lane >> 2, p = lane & 3;
      f16 hv[2];
#pragma unroll
      for (int s = 0; s < 2; ++s) {
        const int u = 2 * p + s;
        const float* z = zone + (u >> 2) * 272;
        const int rq = (u & 3) * 4;
        const float pi = z[(rq + 0) * 17 + b] + biasL0[s][0];
        const float pf = z[(rq + 1) * 17 + b] + biasL0[s][1];
        const float pg = z[(rq + 2) * 17 + b] + biasL0[s][2];
        const float po = z[(rq + 3) * 17 + b] + biasL0[s][3];
        float cc = cL0[s];
        cc = sigmoid_f(pf) * cc + sigmoid_f(pi) * tanh_f(pg);
        cL0[s] = cc;
        hv[s] = (f16)(sigmoid_f(po) * tanh_f(cc));
      }
      unsigned pk;
      __builtin_memcpy(&pk, hv, 4);
      st_agent_u32(ws + kH1Off + ((size_t)r * 2 + half) * kHalfSlot +
                       bh * 256 + b * 16 + p * 4,
                   pk);
      for (int i = lane; i < 544; i += 64) zone[i] = 0.f;   // tiles 0-1
      asm volatile("s_waitcnt vmcnt(0)" ::: "memory");       // record at LLC
      if (lane == 0) st_agent_u32(tagbase + bh * 4, (unsigned)r);
    }

    // ================= L1: D = Wih1 @ h1[r-1] + Whh1 @ h2[r-2] =============
    {
      f32x4 a2 = {0.f, 0.f, 0.f, 0.f}, a3 = {0.f, 0.f, 0.f, 0.f};
#pragma unroll
      for (int i = 0; i < 4; ++i) {
        a2 = __builtin_amdgcn_mfma_f32_16x16x32_f16(wI0[i], bf1[i], a2, 0, 0, 0);
        a3 = __builtin_amdgcn_mfma_f32_16x16x32_f16(wI1[i], bf1[i], a3, 0, 0, 0);
      }
#pragma unroll
      for (int i = 0; i < 4; ++i) {
        a2 = __builtin_amdgcn_mfma_f32_16x16x32_f16(wR0[i], bf2[i], a2, 0, 0, 0);
        a3 = __builtin_amdgcn_mfma_f32_16x16x32_f16(wR1[i], bf2[i], a3, 0, 0, 0);
      }
#pragma unroll
      for (int j = 0; j < 4; ++j) {
        atomicAdd(&zone[2 * 272 + (kg * 4 + j) * 17 + m], a2[j]);
        atomicAdd(&zone[3 * 272 + (kg * 4 + j) * 17 + m], a3[j]);
      }
    }
    // ---- FC: D = Wfc @ h2[r-2]   (rows 0..3 valid -> o = bh*4+row)
    {
      f32x4 a4 = {0.f, 0.f, 0.f, 0.f};
#pragma unroll
      for (int i = 0; i < 4; ++i)
        a4 = __builtin_amdgcn_mfma_f32_16x16x32_f16(wF[i], bf2[i], a4, 0, 0, 0);
      if (kg == 0) {
#pragma unroll
        for (int j = 0; j < 4; ++j)
          atomicAdd(&zone[4 * 272 + j * 17 + m], a4[j]);
      }
    }
    __syncthreads();                      // SYNC_2: L1/FC zones complete

    // ---- wave1: finalize h2[r-1] -> record + tag; zero tiles 2-3
    //      wave2: FC -> out; zero tile 4
    if (w == 1) {
      if (r >= 2) {
        const int b = lane >> 2, p = lane & 3;
        f16 hv[2];
#pragma unroll
        for (int s = 0; s < 2; ++s) {
          const int u = 2 * p + s;
          const float* z = zone + (2 + (u >> 2)) * 272;
          const int rq = (u & 3) * 4;
          const float pi = z[(rq + 0) * 17 + b] + biasL1[s][0];
          const float pf = z[(rq + 1) * 17 + b] + biasL1[s][1];
          const float pg = z[(rq + 2) * 17 + b] + biasL1[s][2];
          const float po = z[(rq + 3) * 17 + b] + biasL1[s][3];
          float cc = cL1[s];
          cc = sigmoid_f(pf) * cc + sigmoid_f(pi) * tanh_f(pg);
          cL1[s] = cc;
          hv[s] = (f16)(sigmoid_f(po) * tanh_f(cc));
        }
        unsigned pk;
        __builtin_memcpy(&pk, hv, 4);
        st_agent_u32(ws + kH2Off + ((size_t)(r - 1) * 2 + half) * kHalfSlot +
                         bh * 256 + b * 16 + p * 4,
                     pk);
      }
      for (int i = lane; i < 544; i += 64) zone[544 + i] = 0.f;  // tiles 2-3
      if (r >= 2) {
        asm volatile("s_waitcnt vmcnt(0)" ::: "memory");
        if (lane == 0)
          st_agent_u32(tagbase + 512 + bh * 4, (unsigned)(r - 1));
      }
    } else if (w == 2) {
      float v = 0.f;
      if (r >= 3) v = zone[4 * 272 + (lane & 3) * 17 + (lane >> 2)] + bfc_l;
      for (int i = lane; i < 272; i += 64) zone[1088 + i] = 0.f;  // tile 4
      if (r >= 3)
        out[((size_t)(half * 16 + (lane >> 2)) * kTR + (r - 3)) * kO +
            bh * 4 + (lane & 3)] = v;
    }
  }
}

extern "C" void kernel_launch(void* const* d_in, const int* in_sizes, int n_in,
                              void* d_out, int out_size, void* d_ws,
                              size_t ws_size, hipStream_t stream) {
  const float* x    = (const float*)d_in[0];
  const float* Wih0 = (const float*)d_in[1];
  const float* Whh0 = (const float*)d_in[2];
  const float* bih0 = (const float*)d_in[3];
  const float* bhh0 = (const float*)d_in[4];
  const float* Wih1 = (const float*)d_in[5];
  const float* Whh1 = (const float*)d_in[6];
  const float* bih1 = (const float*)d_in[7];
  const float* bhh1 = (const float*)d_in[8];
  const float* Wfc  = (const float*)d_in[9];
  const float* bfc  = (const float*)d_in[10];
  float* out = (float*)d_out;
  char* ws   = (char*)d_ws;

  (void)hipFuncSetAttribute((const void*)lstm_mfma_kernel,
                            hipFuncAttributeMaxDynamicSharedMemorySize,
                            kLdsBytes);

  hipLaunchKernelGGL(lstm_init_kernel, dim3(128), dim3(256), 0, stream, ws);
  hipLaunchKernelGGL(lstm_mfma_kernel, dim3(NBLK), dim3(NTHR), kLdsBytes,
                     stream, x, Wih0, Whh0, bih0, bhh0, Wih1, Whh1, bih1,
                     bhh1, Wfc, bfc, out, ws);
}

// Round 8
// 2427.320 us; speedup vs baseline: 3.7994x; 3.3615x over previous
//
#include <hip/hip_runtime.h>
#include <cstdint>
#include <cstddef>

// ============================================================================
// Persistent fused 2-layer LSTM + FC for MI355X (gfx950) — Round 13:
// XCD-CLUSTERED RECURRENCE PIPELINE. R10-R12: round floor ~15us invariant
// under barrier-flavor changes => tail amplification: every round waits on
// max over 128 producers; us-scale detect/post tails x ln(128) dominate.
// Fix: shrink scope + decouple roles. cluster = bk&7 (XCD under round-robin;
// locality hint only — ALL cross-block data is sc1, placement-independent):
//   c0/c1:    L0 half0/1 — 32 blocks, 32 units/block, 4 units/wave x full K.
//             NO zone, NO atomics: in-wave K-accumulation, in-lane gate math
//             (D rows lg*4+j = 4 gates of unit base+lg), c-state in regs.
//             Chain: poll(32) -> stage 32KB -> 40 MFMA -> gates -> shfl-pack
//             -> 16x8B sc1 stores -> drain -> tag.  L0 FREE-RUNS (never
//             waits on L1/FC) => h1 always ready for L1.
//   c2+c4 / c3+c5: L1 half0/1 — 64 blocks, 16 units/block, K=2048 split 2-way
//             across wave pairs (plain-write zone, no atomics). Critical
//             cycle = own h2 chain only, scope 64.
//   c6/c7:    FC half0/1 — 32 blocks, 16 out-cols/block, consumes h2 with
//             lag; per-wave zone slices, wave0 sums; off critical path.
// Tags: one u32 per producing block, 64B stride (no hot lines), sc1 relaxed;
// record store -> vmcnt(0) -> sync -> tag. Consumers plain-load records
// (fresh per-slot addresses, R10-validated; sc1 stores bypass L2 so no stale
// copies exist). Steps t=1..500 (out only needs h2[1..500]).
// ============================================================================

#define NTHR 512

typedef _Float16 f16;
typedef _Float16 f16x8 __attribute__((ext_vector_type(8)));
typedef float f32x4 __attribute__((ext_vector_type(4)));
typedef unsigned long long u64;

namespace {
constexpr int kT = 512, kI = 256, kH = 1024, kO = 512, kTR = 500;
constexpr int kSteps = 500;
constexpr size_t kHalfSlot = 32768;              // 16 b x 1024 u x f16
// ws layout (bytes):
//   [0,2048):        L0 tags half0  (32 x 64B stride)
//   [2048,4096):     L0 tags half1
//   [4096,8192):     L1 tags half0  (64 x 64B stride)
//   [8192,12288):    L1 tags half1
constexpr size_t kTagL0 = 0;
constexpr size_t kTagL1 = 4096;
constexpr size_t kH1Off = 16384;                 // [t][half][b:16][u:1024] f16
constexpr size_t kH2Off = kH1Off + 503ull * 2 * kHalfSlot;
// LDS geometry
constexpr int kRowH = 1048;                      // f16/row (2096B, 16B-align)
constexpr int kRowX = 264;                       // f16/row for x tile
constexpr int kLdsBytes = 2 * 16 * kRowH * 2 + 4 * 16 * 17 * 4;  // 71424 (L1 max)
}

__device__ __forceinline__ unsigned ld_tag(const void* p) {
  return __hip_atomic_load((const unsigned*)p, __ATOMIC_RELAXED,
                           __HIP_MEMORY_SCOPE_AGENT);
}
__device__ __forceinline__ void st_tag(void* p, unsigned v) {
  __hip_atomic_store((unsigned*)p, v, __ATOMIC_RELAXED,
                     __HIP_MEMORY_SCOPE_AGENT);
}
__device__ __forceinline__ void st_rec_u64(void* p, u64 v) {
  __hip_atomic_store((u64*)p, v, __ATOMIC_RELAXED, __HIP_MEMORY_SCOPE_AGENT);
}
__device__ __forceinline__ float sigmoid_f(float x) {
  return __builtin_amdgcn_rcpf(1.f + __expf(-x));
}
__device__ __forceinline__ float tanh_f(float x) {
  return 1.f - 2.f * __builtin_amdgcn_rcpf(1.f + __expf(2.f * x));
}
__device__ __forceinline__ f16x8 load8(const float* p) {
  f16x8 r;
#pragma unroll
  for (int j = 0; j < 8; ++j) r[j] = (f16)p[j];
  return r;
}
// pack 4 per-lane f16 h-values (lanes lg=0..3 over the same b) into one u64
// on lanes lg==0; all lanes compute, only lane<16 stores.
__device__ __forceinline__ u64 pack4(float h, int lg) {
  f16 hv = (f16)h;
  unsigned short us;
  __builtin_memcpy(&us, &hv, 2);
  unsigned own = us;
  unsigned o1 = __shfl_xor((int)own, 16);
  unsigned p32 = (lg & 1) ? ((o1 & 0xffffu) | (own << 16))
                          : ((own & 0xffffu) | (o1 << 16));
  unsigned o2 = (unsigned)__shfl_xor((int)p32, 32);
  return (lg & 2) ? ((u64)o2 | ((u64)p32 << 32))
                  : ((u64)p32 | ((u64)o2 << 32));
}

__global__ void __launch_bounds__(256, 1) lstm_init_kernel(char* ws) {
  const int gid = blockIdx.x * 256 + threadIdx.x;   // 32768 threads
  unsigned* f = (unsigned*)ws;
  if (gid < 4096) f[gid] = 0u;                      // all tag regions
  u64* r1 = (u64*)(ws + kH1Off);                    // slot 0, both halves
  u64* r2 = (u64*)(ws + kH2Off);
  if (gid < 8192) { r1[gid] = 0ull; r2[gid] = 0ull; }
}

__global__ void __launch_bounds__(NTHR, 1) __attribute__((amdgpu_waves_per_eu(2)))
lstm_pipe_kernel(const float* __restrict__ x,
                 const float* __restrict__ Wih0, const float* __restrict__ Whh0,
                 const float* __restrict__ bih0, const float* __restrict__ bhh0,
                 const float* __restrict__ Wih1, const float* __restrict__ Whh1,
                 const float* __restrict__ bih1, const float* __restrict__ bhh1,
                 const float* __restrict__ Wfc, const float* __restrict__ bfc,
                 float* __restrict__ out, char* __restrict__ ws) {
  const int tid = threadIdx.x;
  const int bk = blockIdx.x;
  const int w = tid >> 6;
  const int lane = tid & 63;
  const int m = lane & 15;                  // A row idx / B col (=batch) / D col
  const int kg = lane >> 4;                 // k-group for A/B frags
  const int lg = lane >> 4;                 // D row group
  const int c = bk & 7, rho = bk >> 3;
  extern __shared__ char smem[];

  if (c < 2) {
    // ===================== L0: h1 recurrence, scope 32 =====================
    const int half = c;
    const int q = m >> 2, g = m & 3;
    const int uA = rho * 32 + 4 * w + q;    // A-row unit
    const int uD = rho * 32 + 4 * w + lg;   // D-row unit (gate math/store)
    f16x8 whh[32], wih[8];
#pragma unroll
    for (int kc = 0; kc < 32; ++kc)
      whh[kc] = load8(Whh0 + (size_t)(g * kH + uA) * kH + kc * 32 + kg * 8);
#pragma unroll
    for (int kx = 0; kx < 8; ++kx)
      wih[kx] = load8(Wih0 + (size_t)(g * kH + uA) * kI + kx * 32 + kg * 8);
    float bias[4];
#pragma unroll
    for (int j = 0; j < 4; ++j) bias[j] = bih0[j * kH + uD] + bhh0[j * kH + uD];
    float cst = 0.f;
    f16* ldsH = (f16*)smem;                             // [16][1048]
    f16* ldsX = (f16*)(smem + 16 * kRowH * 2);          // [16][264]
    unsigned* tagMy = (unsigned*)(ws + kTagL0 + (size_t)half * 2048);
    const int xb = tid >> 5, xcol = (tid & 31) * 8;
    const int sb = tid >> 7, so = (tid & 127) * 8;      // h-stage LDS dest

    for (int t = 1; t <= kSteps; ++t) {
      if (w == 7) {                         // poll own cluster: h1[t-1] ready
        const unsigned tgt = (unsigned)(t - 1);
        const unsigned* tp = tagMy + (size_t)(lane & 31) * 16;
        bool done;
        do {
          done = __all((int)(ld_tag(tp) >= tgt));
          if (!done) __builtin_amdgcn_s_sleep(1);
        } while (!done);
      }
      {                                     // x slice -> LDS (tag-independent)
        f16x8 xv = load8(x + ((size_t)(half * 16 + xb) * kT + (t - 1)) * kI + xcol);
        *(f16x8*)(ldsX + xb * kRowX + xcol) = xv;
      }
      __syncthreads();                      // tags observed by whole block
      {                                     // stage h1[t-1] 32KB -> LDS
        const char* rec = ws + kH1Off + ((size_t)(t - 1) * 2 + half) * kHalfSlot;
        f16x8 h0 = *(const f16x8*)(rec + (size_t)tid * 16);
        f16x8 h1v = *(const f16x8*)(rec + (size_t)(tid + 512) * 16);
        f16x8 h2v = *(const f16x8*)(rec + (size_t)(tid + 1024) * 16);
        f16x8 h3v = *(const f16x8*)(rec + (size_t)(tid + 1536) * 16);
        *(f16x8*)(ldsH + (sb + 0) * kRowH + so) = h0;
        *(f16x8*)(ldsH + (sb + 4) * kRowH + so) = h1v;
        *(f16x8*)(ldsH + (sb + 8) * kRowH + so) = h2v;
        *(f16x8*)(ldsH + (sb + 12) * kRowH + so) = h3v;
      }
      __syncthreads();
      f32x4 acc = {0.f, 0.f, 0.f, 0.f};
#pragma unroll
      for (int kc = 0; kc < 32; ++kc) {
        f16x8 bf = *(const f16x8*)(ldsH + m * kRowH + kc * 32 + kg * 8);
        acc = __builtin_amdgcn_mfma_f32_16x16x32_f16(whh[kc], bf, acc, 0, 0, 0);
      }
#pragma unroll
      for (int kx = 0; kx < 8; ++kx) {
        f16x8 bf = *(const f16x8*)(ldsX + m * kRowX + kx * 32 + kg * 8);
        acc = __builtin_amdgcn_mfma_f32_16x16x32_f16(wih[kx], bf, acc, 0, 0, 0);
      }
      // gates (lane holds 4 gates of unit uD, batch m)
      const float pi = acc[0] + bias[0], pf = acc[1] + bias[1];
      const float pg = acc[2] + bias[2], po = acc[3] + bias[3];
      cst = sigmoid_f(pf) * cst + sigmoid_f(pi) * tanh_f(pg);
      const float h = sigmoid_f(po) * tanh_f(cst);
      const u64 pk = pack4(h, lg);
      if (lane < 16) {                      // b = lane, units rho*32+4w..+3
        st_rec_u64(ws + kH1Off + ((size_t)t * 2 + half) * kHalfSlot +
                       (size_t)lane * 2048 + (size_t)(rho * 32 + 4 * w) * 2,
                   pk);
        asm volatile("s_waitcnt vmcnt(0)" ::: "memory");
      }
      __syncthreads();                      // all waves' records drained
      if (tid == 0) st_tag(tagMy + (size_t)rho * 16, (unsigned)t);
    }

  } else if (c < 6) {
    // ===================== L1: h2 recurrence, scope 64 =====================
    const int half = c & 1;
    const int rank = rho + ((c >= 4) ? 32 : 0);   // 0..63
    const int u0 = rank * 16;
    const int rg = w & 3, kh = w >> 2;            // row-group / K-half
    const int q = m >> 2, g = m & 3;
    const int uA = u0 + 4 * rg + q;
    const int uD = u0 + 4 * rg + lg;
    const float* WA = kh ? Whh1 : Wih1;
    f16x8 wa[32];
#pragma unroll
    for (int kc = 0; kc < 32; ++kc)
      wa[kc] = load8(WA + (size_t)(g * kH + uA) * kH + kc * 32 + kg * 8);
    float bias[4];
#pragma unroll
    for (int j = 0; j < 4; ++j) bias[j] = bih1[j * kH + uD] + bhh1[j * kH + uD];
    float cst = 0.f;                              // live on kh==1 waves
    f16* ldsH1 = (f16*)smem;                      // [16][1048] h1[t]
    f16* ldsH2 = (f16*)(smem + 16 * kRowH * 2);   // [16][1048] h2[t-1]
    float* zone = (float*)(smem + 2 * 16 * kRowH * 2);  // [4][16][17]
    unsigned* tagL0h = (unsigned*)(ws + kTagL0 + (size_t)half * 2048);
    unsigned* tagL1h = (unsigned*)(ws + kTagL1 + (size_t)half * 4096);
    const int sb = tid >> 7, so = (tid & 127) * 8;

    for (int t = 1; t <= kSteps; ++t) {
      if (w == 7) {                         // h1[t] from L0, h2[t-1] own group
        const unsigned tgtA = (unsigned)t, tgtB = (unsigned)(t - 1);
        const unsigned* tpB = tagL1h + (size_t)lane * 16;
        const unsigned* tpA = tagL0h + (size_t)(lane & 31) * 16;
        bool done;
        do {
          bool ok = (ld_tag(tpB) >= tgtB);
          if (lane < 32) ok = ok && (ld_tag(tpA) >= tgtA);
          done = __all((int)ok);
          if (!done) __builtin_amdgcn_s_sleep(1);
        } while (!done);
      }
      __syncthreads();
      {                                     // stage h1[t] + h2[t-1]
        const char* r1 = ws + kH1Off + ((size_t)t * 2 + half) * kHalfSlot;
        const char* r2 = ws + kH2Off + ((size_t)(t - 1) * 2 + half) * kHalfSlot;
        f16x8 a0 = *(const f16x8*)(r1 + (size_t)tid * 16);
        f16x8 a1 = *(const f16x8*)(r1 + (size_t)(tid + 512) * 16);
        f16x8 a2 = *(const f16x8*)(r1 + (size_t)(tid + 1024) * 16);
        f16x8 a3 = *(const f16x8*)(r1 + (size_t)(tid + 1536) * 16);
        f16x8 b0 = *(const f16x8*)(r2 + (size_t)tid * 16);
        f16x8 b1 = *(const f16x8*)(r2 + (size_t)(tid + 512) * 16);
        f16x8 b2 = *(const f16x8*)(r2 + (size_t)(tid + 1024) * 16);
        f16x8 b3 = *(const f16x8*)(r2 + (size_t)(tid + 1536) * 16);
        *(f16x8*)(ldsH1 + (sb + 0) * kRowH + so) = a0;
        *(f16x8*)(ldsH1 + (sb + 4) * kRowH + so) = a1;
        *(f16x8*)(ldsH1 + (sb + 8) * kRowH + so) = a2;
        *(f16x8*)(ldsH1 + (sb + 12) * kRowH + so) = a3;
        *(f16x8*)(ldsH2 + (sb + 0) * kRowH + so) = b0;
        *(f16x8*)(ldsH2 + (sb + 4) * kRowH + so) = b1;
        *(f16x8*)(ldsH2 + (sb + 8) * kRowH + so) = b2;
        *(f16x8*)(ldsH2 + (sb + 12) * kRowH + so) = b3;
      }
      __syncthreads();
      const f16* ldsB = kh ? ldsH2 : ldsH1;
      f32x4 acc = {0.f, 0.f, 0.f, 0.f};
#pragma unroll
      for (int kc = 0; kc < 32; ++kc) {
        f16x8 bf = *(const f16x8*)(ldsB + m * kRowH + kc * 32 + kg * 8);
        acc = __builtin_amdgcn_mfma_f32_16x16x32_f16(wa[kc], bf, acc, 0, 0, 0);
      }
      if (kh == 0) {                        // publish h1-part partials
#pragma unroll
        for (int j = 0; j < 4; ++j)
          zone[(rg * 16 + lg * 4 + j) * 17 + m] = acc[j];
      }
      __syncthreads();                      // zone ready
      if (kh == 1) {                        // combine + gates + store
        const float pi = acc[0] + zone[(rg * 16 + lg * 4 + 0) * 17 + m] + bias[0];
        const float pf = acc[1] + zone[(rg * 16 + lg * 4 + 1) * 17 + m] + bias[1];
        const float pg = acc[2] + zone[(rg * 16 + lg * 4 + 2) * 17 + m] + bias[2];
        const float po = acc[3] + zone[(rg * 16 + lg * 4 + 3) * 17 + m] + bias[3];
        cst = sigmoid_f(pf) * cst + sigmoid_f(pi) * tanh_f(pg);
        const float h = sigmoid_f(po) * tanh_f(cst);
        const u64 pk = pack4(h, lg);
        if (lane < 16) {
          st_rec_u64(ws + kH2Off + ((size_t)t * 2 + half) * kHalfSlot +
                         (size_t)lane * 2048 + (size_t)(u0 + 4 * rg) * 2,
                     pk);
          asm volatile("s_waitcnt vmcnt(0)" ::: "memory");
        }
      }
      __syncthreads();                      // records drained
      if (tid == 0) st_tag(tagL1h + (size_t)rank * 16, (unsigned)t);
    }

  } else {
    // ===================== FC: out = Wfc @ h2[t] + b =======================
    const int half = c - 6;
    const int o0 = rho * 16;
    f16x8 wf[4];
#pragma unroll
    for (int i = 0; i < 4; ++i)
      wf[i] = load8(Wfc + (size_t)(o0 + m) * kH + (size_t)(w + 8 * i) * 32 + kg * 8);
    f16* ldsH = (f16*)smem;                        // [16][1048] h2[t]
    float* zone = (float*)(smem + 16 * kRowH * 2); // [8][16][17] per-wave
    unsigned* tagL1h = (unsigned*)(ws + kTagL1 + (size_t)half * 4096);
    const int sb = tid >> 7, so = (tid & 127) * 8;
    // wave0 store indices
    const int ob = lane >> 2, op = lane & 3;
    float4 bf4;
    if (w == 0) bf4 = *(const float4*)(bfc + o0 + op * 4);

    for (int t = 1; t <= kSteps; ++t) {
      if (w == 7) {
        const unsigned tgt = (unsigned)t;
        const unsigned* tp = tagL1h + (size_t)lane * 16;
        bool done;
        do {
          done = __all((int)(ld_tag(tp) >= tgt));
          if (!done) __builtin_amdgcn_s_sleep(1);
        } while (!done);
      }
      __syncthreads();
      {
        const char* r2 = ws + kH2Off + ((size_t)t * 2 + half) * kHalfSlot;
        f16x8 b0 = *(const f16x8*)(r2 + (size_t)tid * 16);
        f16x8 b1 = *(const f16x8*)(r2 + (size_t)(tid + 512) * 16);
        f16x8 b2 = *(const f16x8*)(r2 + (size_t)(tid + 1024) * 16);
        f16x8 b3 = *(const f16x8*)(r2 + (size_t)(tid + 1536) * 16);
        *(f16x8*)(ldsH + (sb + 0) * kRowH + so) = b0;
        *(f16x8*)(ldsH + (sb + 4) * kRowH + so) = b1;
        *(f16x8*)(ldsH + (sb + 8) * kRowH + so) = b2;
        *(f16x8*)(ldsH + (sb + 12) * kRowH + so) = b3;
      }
      __syncthreads();
      f32x4 acc = {0.f, 0.f, 0.f, 0.f};
#pragma unroll
      for (int i = 0; i < 4; ++i) {
        f16x8 bf = *(const f16x8*)(ldsH + m * kRowH + (w + 8 * i) * 32 + kg * 8);
        acc = __builtin_amdgcn_mfma_f32_16x16x32_f16(wf[i], bf, acc, 0, 0, 0);
      }
#pragma unroll
      for (int j = 0; j < 4; ++j)
        zone[(w * 16 + lg * 4 + j) * 17 + m] = acc[j];    // per-wave slice
      __syncthreads();
      if (w == 0) {                          // sum 8 slices, + bias, store
        float4 v;
#pragma unroll
        for (int jj = 0; jj < 4; ++jj) {
          float s = 0.f;
#pragma unroll
          for (int ww = 0; ww < 8; ++ww)
            s += zone[(ww * 16 + op * 4 + jj) * 17 + ob];
          ((float*)&v)[jj] = s + ((const float*)&bf4)[jj];
        }
        *(float4*)(out + ((size_t)(half * 16 + ob) * kTR + (t - 1)) * kO +
                   o0 + op * 4) = v;
      }
    }
  }
}

extern "C" void kernel_launch(void* const* d_in, const int* in_sizes, int n_in,
                              void* d_out, int out_size, void* d_ws,
                              size_t ws_size, hipStream_t stream) {
  const float* x    = (const float*)d_in[0];
  const float* Wih0 = (const float*)d_in[1];
  const float* Whh0 = (const float*)d_in[2];
  const float* bih0 = (const float*)d_in[3];
  const float* bhh0 = (const float*)d_in[4];
  const float* Wih1 = (const float*)d_in[5];
  const float* Whh1 = (const float*)d_in[6];
  const float* bih1 = (const float*)d_in[7];
  const float* bhh1 = (const float*)d_in[8];
  const float* Wfc  = (const float*)d_in[9];
  const float* bfc  = (const float*)d_in[10];
  float* out = (float*)d_out;
  char* ws   = (char*)d_ws;

  (void)hipFuncSetAttribute((const void*)lstm_pipe_kernel,
                            hipFuncAttributeMaxDynamicSharedMemorySize,
                            kLdsBytes);

  hipLaunchKernelGGL(lstm_init_kernel, dim3(128), dim3(256), 0, stream, ws);
  hipLaunchKernelGGL(lstm_pipe_kernel, dim3(256), dim3(NTHR), kLdsBytes,
                     stream, x, Wih0, Whh0, bih0, bhh0, Wih1, Whh1, bih1,
                     bhh1, Wfc, bfc, out, ws);
}